// Round 6
// baseline (279.294 us; speedup 1.0000x reference)
//
#include <hip/hip_runtime.h>
#include <math.h>

// ReRanker fused single-kernel, v2 (pure-stream passes): B=256, C=128, D=1024.
// inner via Gram factorization: sum_k cos(c,k) = dot(chat_c, sum_k chat_k).
// One block per b (256 blocks = 1/CU), 1024 threads (16 waves).
// Pass A (HBM): per-lane partials cc/cd/cs for 8 cand/wave - NO shuffles in loop.
// Batched butterfly -> icv[8] in regs. Pass B (L3): s_prv += cv*icv, pure FMA.
// Pass C (L3): td[8] partials, batched butterfly -> inner. Deterministic.

#define EPS 1e-8f
constexpr int B = 256;
constexpr int C = 128;
constexpr int D = 1024;
constexpr int NW = 16;        // waves per block
constexpr int CPW = C / NW;   // 8 candidate rows per wave

__device__ __forceinline__ float dot4(const float4 a, const float4 b) {
    return a.x * b.x + a.y * b.y + a.z * b.z + a.w * b.w;
}

__global__ __launch_bounds__(1024) void rerank_all(
    const float* __restrict__ doc, const float* __restrict__ summ,
    const float* __restrict__ cand, float* __restrict__ out_outer,
    float* __restrict__ out_inner, float* __restrict__ out_sumscore,
    float* __restrict__ out_sumavg) {
    const int b = blockIdx.x;
    const int t = threadIdx.x;
    const int wave = t >> 6;
    const int lane = t & 63;

    __shared__ float s_part[NW][D];  // 64 KiB per-wave partial column sums
    __shared__ float s_full[D];      // 4 KiB reduced column sum
    __shared__ float sa_lds[NW];     // per-wave summary_avg partials

    // ---- Phase 1: doc/summary norms + summary_score (wave-uniform) ----
    const float4* dp = (const float4*)(doc + (size_t)b * D);
    const float4* sp = (const float4*)(summ + (size_t)b * D);
    float4 d4[4], m4[4];
#pragma unroll
    for (int q = 0; q < 4; ++q) {
        d4[q] = dp[lane + 64 * q];
        m4[q] = sp[lane + 64 * q];
    }
    float dd = 0.0f, ss = 0.0f, sd = 0.0f;
#pragma unroll
    for (int q = 0; q < 4; ++q) {
        dd += dot4(d4[q], d4[q]);
        ss += dot4(m4[q], m4[q]);
        sd += dot4(m4[q], d4[q]);
    }
#pragma unroll
    for (int lv = 1; lv <= 32; lv <<= 1) {
        dd += __shfl_xor(dd, lv, 64);
        ss += __shfl_xor(ss, lv, 64);
        sd += __shfl_xor(sd, lv, 64);
    }
    const float di = 1.0f / fmaxf(sqrtf(dd), EPS);
    const float si = 1.0f / fmaxf(sqrtf(ss), EPS);
    if (t == 0) out_sumscore[b] = sd * di * si;

    const float4* cb = (const float4*)(cand + (size_t)b * C * D);

    // ---- Pass A: pure-stream partial dots (cc, cd, cs) for 8 candidates ----
    float cc[CPW], cd[CPW], cs[CPW];
#pragma unroll
    for (int i = 0; i < CPW; ++i) { cc[i] = 0.f; cd[i] = 0.f; cs[i] = 0.f; }
#pragma unroll
    for (int i = 0; i < CPW; ++i) {
        const float4* cp = cb + (size_t)(wave * CPW + i) * (D / 4);
        float4 cv[4];
#pragma unroll
        for (int q = 0; q < 4; ++q) cv[q] = cp[lane + 64 * q];
#pragma unroll
        for (int q = 0; q < 4; ++q) {
            cc[i] += dot4(cv[q], cv[q]);
            cd[i] += dot4(cv[q], d4[q]);
            cs[i] += dot4(cv[q], m4[q]);
        }
    }
    // batched butterfly: 24 independent chains, pipelined per level
#pragma unroll
    for (int lv = 1; lv <= 32; lv <<= 1) {
#pragma unroll
        for (int i = 0; i < CPW; ++i) {
            cc[i] += __shfl_xor(cc[i], lv, 64);
            cd[i] += __shfl_xor(cd[i], lv, 64);
            cs[i] += __shfl_xor(cs[i], lv, 64);
        }
    }
    float icv[CPW];
    float sa_acc = 0.0f;
#pragma unroll
    for (int i = 0; i < CPW; ++i) {
        icv[i] = 1.0f / fmaxf(sqrtf(cc[i]), EPS);
        sa_acc += cs[i] * icv[i];
    }
    if (lane == 0) {
#pragma unroll
        for (int i = 0; i < CPW; ++i)
            out_outer[b * C + wave * CPW + i] = cd[i] * icv[i] * di;
        sa_lds[wave] = sa_acc;
    }

    // ---- Pass B: weighted column sum, pure FMA stream (L3-hot re-read) ----
    float4 s_prv[4];
#pragma unroll
    for (int q = 0; q < 4; ++q) s_prv[q] = make_float4(0.f, 0.f, 0.f, 0.f);
#pragma unroll
    for (int i = 0; i < CPW; ++i) {
        const float4* cp = cb + (size_t)(wave * CPW + i) * (D / 4);
        const float w = icv[i];
#pragma unroll
        for (int q = 0; q < 4; ++q) {
            const float4 cv = cp[lane + 64 * q];
            s_prv[q].x += cv.x * w;
            s_prv[q].y += cv.y * w;
            s_prv[q].z += cv.z * w;
            s_prv[q].w += cv.w * w;
        }
    }
#pragma unroll
    for (int q = 0; q < 4; ++q)
        ((float4*)s_part[wave])[lane + 64 * q] = s_prv[q];
    __syncthreads();

    // reduce 16 wave partials: thread t owns column t (conflict-free)
    float colsum = 0.0f;
#pragma unroll
    for (int w = 0; w < NW; ++w) colsum += s_part[w][t];
    s_full[t] = colsum;
    if (t == 0) {
        float S = 0.0f;
#pragma unroll
        for (int w = 0; w < NW; ++w) S += sa_lds[w];
        out_sumavg[b] = S * si * (1.0f / C);
    }
    __syncthreads();

    // ---- Pass C: td = dot(cand_c, s), pure stream + batched butterfly ----
    float4 s4[4];
#pragma unroll
    for (int q = 0; q < 4; ++q) s4[q] = ((const float4*)s_full)[lane + 64 * q];

    float td[CPW];
#pragma unroll
    for (int i = 0; i < CPW; ++i) td[i] = 0.f;
#pragma unroll
    for (int i = 0; i < CPW; ++i) {
        const float4* cp = cb + (size_t)(wave * CPW + i) * (D / 4);
#pragma unroll
        for (int q = 0; q < 4; ++q) {
            const float4 cv = cp[lane + 64 * q];
            td[i] += dot4(cv, s4[q]);
        }
    }
#pragma unroll
    for (int lv = 1; lv <= 32; lv <<= 1) {
#pragma unroll
        for (int i = 0; i < CPW; ++i) td[i] += __shfl_xor(td[i], lv, 64);
    }
    if (lane == 0) {
#pragma unroll
        for (int i = 0; i < CPW; ++i)
            out_inner[b * C + wave * CPW + i] =
                (td[i] * icv[i] - 1.0f) * (1.0f / (C - 1));
    }
}

extern "C" void kernel_launch(void* const* d_in, const int* in_sizes, int n_in,
                              void* d_out, int out_size, void* d_ws,
                              size_t ws_size, hipStream_t stream) {
    const float* doc = (const float*)d_in[0];   // [B, D]
    const float* summ = (const float*)d_in[1];  // [B, D]
    const float* cand = (const float*)d_in[2];  // [B, C, D]

    float* out = (float*)d_out;
    float* out_outer = out;                    // [B*C]
    float* out_inner = out + B * C;            // [B*C]
    float* out_sumscore = out + 2 * B * C;     // [B]
    float* out_sumavg = out + 2 * B * C + B;   // [B]

    rerank_all<<<B, 1024, 0, stream>>>(doc, summ, cand, out_outer, out_inner,
                                       out_sumscore, out_sumavg);
}

// Round 7
// 278.641 us; speedup vs baseline: 1.0023x; 1.0023x over previous
//
#include <hip/hip_runtime.h>
#include <math.h>

// ReRanker fused single-kernel, v3: B=256, C=128, D=1024, f32.
// v2 (pure-stream passes) + __launch_bounds__(1024,4): 4 waves/EU -> 1 block/CU
// -> 128-VGPR budget, eliminating the v2 scratch spills (WRITE_SIZE 160MB).
// inner via Gram factorization: sum_k cos(c,k) = dot(chat_c, sum_k chat_k).
// Pass A (HBM): per-lane partials cc/cd/cs for 8 cand/wave - no shuffles in loop.
// Batched butterfly -> icv[8] in regs. Pass B (L2/L3): s_prv += cv*icv, pure FMA.
// Pass C (L2/L3): td[8] partials, batched butterfly -> inner. Deterministic.

#define EPS 1e-8f
constexpr int B = 256;
constexpr int C = 128;
constexpr int D = 1024;
constexpr int NW = 16;        // waves per block
constexpr int CPW = C / NW;   // 8 candidate rows per wave

__device__ __forceinline__ float dot4(const float4 a, const float4 b) {
    return a.x * b.x + a.y * b.y + a.z * b.z + a.w * b.w;
}

__global__ __launch_bounds__(1024, 4) void rerank_all(
    const float* __restrict__ doc, const float* __restrict__ summ,
    const float* __restrict__ cand, float* __restrict__ out_outer,
    float* __restrict__ out_inner, float* __restrict__ out_sumscore,
    float* __restrict__ out_sumavg) {
    const int b = blockIdx.x;
    const int t = threadIdx.x;
    const int wave = t >> 6;
    const int lane = t & 63;

    __shared__ float s_part[NW][D];  // 64 KiB per-wave partial column sums
    __shared__ float s_full[D];      // 4 KiB reduced column sum
    __shared__ float sa_lds[NW];     // per-wave summary_avg partials

    // ---- Phase 1: doc/summary norms + summary_score (wave-uniform) ----
    const float4* dp = (const float4*)(doc + (size_t)b * D);
    const float4* sp = (const float4*)(summ + (size_t)b * D);
    float4 d4[4], m4[4];
#pragma unroll
    for (int q = 0; q < 4; ++q) {
        d4[q] = dp[lane + 64 * q];
        m4[q] = sp[lane + 64 * q];
    }
    float dd = 0.0f, ss = 0.0f, sd = 0.0f;
#pragma unroll
    for (int q = 0; q < 4; ++q) {
        dd += dot4(d4[q], d4[q]);
        ss += dot4(m4[q], m4[q]);
        sd += dot4(m4[q], d4[q]);
    }
#pragma unroll
    for (int lv = 1; lv <= 32; lv <<= 1) {
        dd += __shfl_xor(dd, lv, 64);
        ss += __shfl_xor(ss, lv, 64);
        sd += __shfl_xor(sd, lv, 64);
    }
    const float di = 1.0f / fmaxf(sqrtf(dd), EPS);
    const float si = 1.0f / fmaxf(sqrtf(ss), EPS);
    if (t == 0) out_sumscore[b] = sd * di * si;

    const float4* cb = (const float4*)(cand + (size_t)b * C * D);

    // ---- Pass A: pure-stream partial dots (cc, cd, cs) for 8 candidates ----
    float cc[CPW], cd[CPW], cs[CPW];
#pragma unroll
    for (int i = 0; i < CPW; ++i) { cc[i] = 0.f; cd[i] = 0.f; cs[i] = 0.f; }
#pragma unroll
    for (int i = 0; i < CPW; ++i) {
        const float4* cp = cb + (size_t)(wave * CPW + i) * (D / 4);
        float4 cv[4];
#pragma unroll
        for (int q = 0; q < 4; ++q) cv[q] = cp[lane + 64 * q];
#pragma unroll
        for (int q = 0; q < 4; ++q) {
            cc[i] += dot4(cv[q], cv[q]);
            cd[i] += dot4(cv[q], d4[q]);
            cs[i] += dot4(cv[q], m4[q]);
        }
    }
    // batched butterfly: 24 independent chains, pipelined per level
#pragma unroll
    for (int lv = 1; lv <= 32; lv <<= 1) {
#pragma unroll
        for (int i = 0; i < CPW; ++i) {
            cc[i] += __shfl_xor(cc[i], lv, 64);
            cd[i] += __shfl_xor(cd[i], lv, 64);
            cs[i] += __shfl_xor(cs[i], lv, 64);
        }
    }
    float icv[CPW];
    float sa_acc = 0.0f;
#pragma unroll
    for (int i = 0; i < CPW; ++i) {
        icv[i] = 1.0f / fmaxf(sqrtf(cc[i]), EPS);
        sa_acc += cs[i] * icv[i];
    }
    if (lane == 0) {
#pragma unroll
        for (int i = 0; i < CPW; ++i)
            out_outer[b * C + wave * CPW + i] = cd[i] * icv[i] * di;
        sa_lds[wave] = sa_acc;
    }

    // ---- Pass B: weighted column sum, pure FMA stream (L2/L3-hot re-read) ----
    float4 s_prv[4];
#pragma unroll
    for (int q = 0; q < 4; ++q) s_prv[q] = make_float4(0.f, 0.f, 0.f, 0.f);
#pragma unroll
    for (int i = 0; i < CPW; ++i) {
        const float4* cp = cb + (size_t)(wave * CPW + i) * (D / 4);
        const float w = icv[i];
#pragma unroll
        for (int q = 0; q < 4; ++q) {
            const float4 cv = cp[lane + 64 * q];
            s_prv[q].x += cv.x * w;
            s_prv[q].y += cv.y * w;
            s_prv[q].z += cv.z * w;
            s_prv[q].w += cv.w * w;
        }
    }
#pragma unroll
    for (int q = 0; q < 4; ++q)
        ((float4*)s_part[wave])[lane + 64 * q] = s_prv[q];
    __syncthreads();

    // reduce 16 wave partials: thread t owns column t (conflict-free)
    float colsum = 0.0f;
#pragma unroll
    for (int w = 0; w < NW; ++w) colsum += s_part[w][t];
    s_full[t] = colsum;
    if (t == 0) {
        float S = 0.0f;
#pragma unroll
        for (int w = 0; w < NW; ++w) S += sa_lds[w];
        out_sumavg[b] = S * si * (1.0f / C);
    }
    __syncthreads();

    // ---- Pass C: td = dot(cand_c, s), pure stream + batched butterfly ----
    float4 s4[4];
#pragma unroll
    for (int q = 0; q < 4; ++q) s4[q] = ((const float4*)s_full)[lane + 64 * q];

    float td[CPW];
#pragma unroll
    for (int i = 0; i < CPW; ++i) td[i] = 0.f;
#pragma unroll
    for (int i = 0; i < CPW; ++i) {
        const float4* cp = cb + (size_t)(wave * CPW + i) * (D / 4);
#pragma unroll
        for (int q = 0; q < 4; ++q) {
            const float4 cv = cp[lane + 64 * q];
            td[i] += dot4(cv, s4[q]);
        }
    }
#pragma unroll
    for (int lv = 1; lv <= 32; lv <<= 1) {
#pragma unroll
        for (int i = 0; i < CPW; ++i) td[i] += __shfl_xor(td[i], lv, 64);
    }
    if (lane == 0) {
#pragma unroll
        for (int i = 0; i < CPW; ++i)
            out_inner[b * C + wave * CPW + i] =
                (td[i] * icv[i] - 1.0f) * (1.0f / (C - 1));
    }
}

extern "C" void kernel_launch(void* const* d_in, const int* in_sizes, int n_in,
                              void* d_out, int out_size, void* d_ws,
                              size_t ws_size, hipStream_t stream) {
    const float* doc = (const float*)d_in[0];   // [B, D]
    const float* summ = (const float*)d_in[1];  // [B, D]
    const float* cand = (const float*)d_in[2];  // [B, C, D]

    float* out = (float*)d_out;
    float* out_outer = out;                    // [B*C]
    float* out_inner = out + B * C;            // [B*C]
    float* out_sumscore = out + 2 * B * C;     // [B]
    float* out_sumavg = out + 2 * B * C + B;   // [B]

    rerank_all<<<B, 1024, 0, stream>>>(doc, summ, cand, out_outer, out_inner,
                                       out_sumscore, out_sumavg);
}

// Round 9
// 270.913 us; speedup vs baseline: 1.0309x; 1.0285x over previous
//
#include <hip/hip_runtime.h>
#include <math.h>

// ReRanker fused single-kernel, v4: B=256, C=128, D=1024, f32.
// Lesson from v2/v3: with 1024-thr blocks the allocator pins at 64 VGPR and
// spills (160MB scratch). v4 fits the pure-stream structure IN 64 VGPRs:
// doc/summ rows live in LDS (not 32 regs), s read from LDS in pass C, all
// array loops fully unrolled (no runtime indexing -> no scratch).
// inner via Gram factorization: sum_k cos(c,k) = dot(chat_c, sum_k chat_k).
// Pass A (HBM): cc/cd/cs partials, no shuffles in loop; batched butterfly.
// Pass B (L3): s_prv += cv*icv. Pass C (L3): td partials + butterfly.

#define EPS 1e-8f
constexpr int B = 256;
constexpr int C = 128;
constexpr int D = 1024;
constexpr int NW = 16;        // waves per block
constexpr int CPW = C / NW;   // 8 candidate rows per wave

__device__ __forceinline__ float dot4(const float4 a, const float4 b) {
    return a.x * b.x + a.y * b.y + a.z * b.z + a.w * b.w;
}

__global__ __launch_bounds__(1024) void rerank_all(
    const float* __restrict__ doc, const float* __restrict__ summ,
    const float* __restrict__ cand, float* __restrict__ out_outer,
    float* __restrict__ out_inner, float* __restrict__ out_sumscore,
    float* __restrict__ out_sumavg) {
    const int b = blockIdx.x;
    const int t = threadIdx.x;
    const int wave = t >> 6;
    const int lane = t & 63;

    __shared__ float4 dmd[D / 4];    // doc row, 4 KiB
    __shared__ float4 dms[D / 4];    // summ row, 4 KiB
    __shared__ float s_part[NW][D];  // 64 KiB per-wave partial column sums
    __shared__ float s_full[D];      // 4 KiB reduced column sum
    __shared__ float sa_lds[NW];     // per-wave summary_avg partials

    // ---- Stage doc+summ rows to LDS (coalesced, threads 0..511) ----
    if (t < 256) dmd[t] = ((const float4*)(doc + (size_t)b * D))[t];
    else if (t < 512) dms[t - 256] = ((const float4*)(summ + (size_t)b * D))[t - 256];
    __syncthreads();

    // ---- Phase 1: doc/summary norms (each wave, from LDS; wave-uniform) ----
    float dd = 0.0f, ss = 0.0f, sd = 0.0f;
#pragma unroll
    for (int q = 0; q < 4; ++q) {
        const float4 d = dmd[lane + 64 * q];
        const float4 m = dms[lane + 64 * q];
        dd += dot4(d, d);
        ss += dot4(m, m);
        sd += dot4(m, d);
    }
#pragma unroll
    for (int lv = 1; lv <= 32; lv <<= 1) {
        dd += __shfl_xor(dd, lv, 64);
        ss += __shfl_xor(ss, lv, 64);
        sd += __shfl_xor(sd, lv, 64);
    }
    const float di = 1.0f / fmaxf(sqrtf(dd), EPS);
    const float si = 1.0f / fmaxf(sqrtf(ss), EPS);
    if (t == 0) out_sumscore[b] = sd * di * si;

    const float4* cb = (const float4*)(cand + (size_t)b * C * D);

    // ---- Pass A: pure-stream partial dots (cc, cd, cs), 8 candidates ----
    float cc[CPW], cd[CPW], cs[CPW];
#pragma unroll
    for (int i = 0; i < CPW; ++i) {
        const float4* cp = cb + (size_t)(wave * CPW + i) * (D / 4);
        float a0 = 0.f, a1 = 0.f, a2 = 0.f;
#pragma unroll
        for (int q = 0; q < 4; ++q) {
            const float4 cv = cp[lane + 64 * q];
            const float4 d = dmd[lane + 64 * q];
            const float4 m = dms[lane + 64 * q];
            a0 += dot4(cv, cv);
            a1 += dot4(cv, d);
            a2 += dot4(cv, m);
        }
        cc[i] = a0; cd[i] = a1; cs[i] = a2;
    }
    // batched butterfly: 24 independent chains, pipelined per level
#pragma unroll
    for (int lv = 1; lv <= 32; lv <<= 1) {
#pragma unroll
        for (int i = 0; i < CPW; ++i) {
            cc[i] += __shfl_xor(cc[i], lv, 64);
            cd[i] += __shfl_xor(cd[i], lv, 64);
            cs[i] += __shfl_xor(cs[i], lv, 64);
        }
    }
    float icv[CPW];
    float sa_acc = 0.0f;
#pragma unroll
    for (int i = 0; i < CPW; ++i) {
        icv[i] = 1.0f / fmaxf(sqrtf(cc[i]), EPS);
        sa_acc += cs[i] * icv[i];
    }
    if (lane == 0) {
#pragma unroll
        for (int i = 0; i < CPW; ++i)
            out_outer[b * C + wave * CPW + i] = cd[i] * icv[i] * di;
        sa_lds[wave] = sa_acc;
    }

    // ---- Pass B: weighted column sum, pure FMA stream (L3-hot re-read) ----
    float4 s_prv[4];
#pragma unroll
    for (int q = 0; q < 4; ++q) s_prv[q] = make_float4(0.f, 0.f, 0.f, 0.f);
#pragma unroll
    for (int i = 0; i < CPW; ++i) {
        const float4* cp = cb + (size_t)(wave * CPW + i) * (D / 4);
        const float w = icv[i];
#pragma unroll
        for (int q = 0; q < 4; ++q) {
            const float4 cv = cp[lane + 64 * q];
            s_prv[q].x += cv.x * w;
            s_prv[q].y += cv.y * w;
            s_prv[q].z += cv.z * w;
            s_prv[q].w += cv.w * w;
        }
    }
#pragma unroll
    for (int q = 0; q < 4; ++q)
        ((float4*)s_part[wave])[lane + 64 * q] = s_prv[q];
    __syncthreads();

    // reduce 16 wave partials: thread t owns column t (conflict-free)
    float colsum = 0.0f;
#pragma unroll
    for (int w = 0; w < NW; ++w) colsum += s_part[w][t];
    s_full[t] = colsum;
    if (t == 0) {
        float S = 0.0f;
#pragma unroll
        for (int w = 0; w < NW; ++w) S += sa_lds[w];
        out_sumavg[b] = S * si * (1.0f / C);
    }
    __syncthreads();

    // ---- Pass C: td = dot(cand_c, s) with s from LDS, batched butterfly ----
    float td[CPW];
#pragma unroll
    for (int i = 0; i < CPW; ++i) {
        const float4* cp = cb + (size_t)(wave * CPW + i) * (D / 4);
        float a = 0.f;
#pragma unroll
        for (int q = 0; q < 4; ++q) {
            const float4 cv = cp[lane + 64 * q];
            const float4 sv = ((const float4*)s_full)[lane + 64 * q];
            a += dot4(cv, sv);
        }
        td[i] = a;
    }
#pragma unroll
    for (int lv = 1; lv <= 32; lv <<= 1) {
#pragma unroll
        for (int i = 0; i < CPW; ++i) td[i] += __shfl_xor(td[i], lv, 64);
    }
    if (lane == 0) {
#pragma unroll
        for (int i = 0; i < CPW; ++i)
            out_inner[b * C + wave * CPW + i] =
                (td[i] * icv[i] - 1.0f) * (1.0f / (C - 1));
    }
}

extern "C" void kernel_launch(void* const* d_in, const int* in_sizes, int n_in,
                              void* d_out, int out_size, void* d_ws,
                              size_t ws_size, hipStream_t stream) {
    const float* doc = (const float*)d_in[0];   // [B, D]
    const float* summ = (const float*)d_in[1];  // [B, D]
    const float* cand = (const float*)d_in[2];  // [B, C, D]

    float* out = (float*)d_out;
    float* out_outer = out;                    // [B*C]
    float* out_inner = out + B * C;            // [B*C]
    float* out_sumscore = out + 2 * B * C;     // [B]
    float* out_sumavg = out + 2 * B * C + B;   // [B]

    rerank_all<<<B, 1024, 0, stream>>>(doc, summ, cand, out_outer, out_inner,
                                       out_sumscore, out_sumavg);
}

// Round 10
// 216.853 us; speedup vs baseline: 1.2879x; 1.2493x over previous
//
#include <hip/hip_runtime.h>
#include <math.h>

// ReRanker fused single-kernel, v5: B=256, C=128, D=1024, f32.
// Spill fix: live set kept < 64 VGPR by (1) pairwise candidate processing
// (6-wide accumulators, 6-chain batched butterflies), (2) fusing the weighted
// column-sum into pass A via LDS read-modify-write on the wave-private
// s_part[wave] row (no 16-reg s_prv), (3) icv via LDS not an 8-reg array.
// Two candidate passes total: A (HBM) computes norms/dots/outer/s;
// C (L3-hot re-read) computes inner = (dot(c,s)*ic - 1)/(C-1).
// inner via Gram factorization: sum_k cos(c,k) = dot(chat_c, sum_k chat_k).

#define EPS 1e-8f
constexpr int B = 256;
constexpr int C = 128;
constexpr int D = 1024;
constexpr int NW = 16;        // waves per block
constexpr int CPW = C / NW;   // 8 candidate rows per wave

__device__ __forceinline__ float dot4(const float4 a, const float4 b) {
    return a.x * b.x + a.y * b.y + a.z * b.z + a.w * b.w;
}

__global__ __launch_bounds__(1024) void rerank_all(
    const float* __restrict__ doc, const float* __restrict__ summ,
    const float* __restrict__ cand, float* __restrict__ out_outer,
    float* __restrict__ out_inner, float* __restrict__ out_sumscore,
    float* __restrict__ out_sumavg) {
    const int b = blockIdx.x;
    const int t = threadIdx.x;
    const int wave = t >> 6;
    const int lane = t & 63;

    __shared__ float4 dmd[D / 4];    // doc row, 4 KiB
    __shared__ float4 dms[D / 4];    // summ row, 4 KiB
    __shared__ float s_part[NW][D];  // 64 KiB per-wave partial column sums
    __shared__ float s_full[D];      // 4 KiB reduced column sum
    __shared__ float ic_lds[C];      // 0.5 KiB 1/||cand||
    __shared__ float sa_lds[NW];     // per-wave summary_avg partials

    // ---- Stage doc+summ rows to LDS (coalesced) ----
    if (t < 256) dmd[t] = ((const float4*)(doc + (size_t)b * D))[t];
    else if (t < 512) dms[t - 256] = ((const float4*)(summ + (size_t)b * D))[t - 256];
    // zero this wave's s_part row (wave-private, no cross-wave hazard)
#pragma unroll
    for (int q = 0; q < 4; ++q)
        ((float4*)s_part[wave])[lane + 64 * q] = make_float4(0.f, 0.f, 0.f, 0.f);
    __syncthreads();

    // ---- Phase 1: doc/summary norms (from LDS; wave-uniform result) ----
    float dd = 0.0f, ss = 0.0f, sd = 0.0f;
#pragma unroll
    for (int q = 0; q < 4; ++q) {
        const float4 d = dmd[lane + 64 * q];
        const float4 m = dms[lane + 64 * q];
        dd += dot4(d, d);
        ss += dot4(m, m);
        sd += dot4(m, d);
    }
#pragma unroll
    for (int lv = 1; lv <= 32; lv <<= 1) {
        dd += __shfl_xor(dd, lv, 64);
        ss += __shfl_xor(ss, lv, 64);
        sd += __shfl_xor(sd, lv, 64);
    }
    const float di = 1.0f / fmaxf(sqrtf(dd), EPS);
    const float si = 1.0f / fmaxf(sqrtf(ss), EPS);
    if (t == 0) out_sumscore[b] = sd * di * si;

    const float4* cb = (const float4*)(cand + (size_t)b * C * D);
    float* sw = s_part[wave];

    // ---- Pass A (HBM, fused with s-accumulation): pairwise candidates ----
    float sa_acc = 0.0f;
#pragma unroll
    for (int p = 0; p < CPW / 2; ++p) {
        const int c0 = wave * CPW + 2 * p;
        const float4* cp0 = cb + (size_t)c0 * (D / 4);
        const float4* cp1 = cp0 + (D / 4);
        float4 cv0[4], cv1[4];
#pragma unroll
        for (int q = 0; q < 4; ++q) {
            cv0[q] = cp0[lane + 64 * q];
            cv1[q] = cp1[lane + 64 * q];
        }
        float cc0 = 0.f, cd0 = 0.f, cs0 = 0.f;
        float cc1 = 0.f, cd1 = 0.f, cs1 = 0.f;
#pragma unroll
        for (int q = 0; q < 4; ++q) {
            const float4 d = dmd[lane + 64 * q];
            const float4 m = dms[lane + 64 * q];
            cc0 += dot4(cv0[q], cv0[q]);
            cd0 += dot4(cv0[q], d);
            cs0 += dot4(cv0[q], m);
            cc1 += dot4(cv1[q], cv1[q]);
            cd1 += dot4(cv1[q], d);
            cs1 += dot4(cv1[q], m);
        }
        // batched butterfly: 6 independent chains
#pragma unroll
        for (int lv = 1; lv <= 32; lv <<= 1) {
            cc0 += __shfl_xor(cc0, lv, 64);
            cd0 += __shfl_xor(cd0, lv, 64);
            cs0 += __shfl_xor(cs0, lv, 64);
            cc1 += __shfl_xor(cc1, lv, 64);
            cd1 += __shfl_xor(cd1, lv, 64);
            cs1 += __shfl_xor(cs1, lv, 64);
        }
        const float icv0 = 1.0f / fmaxf(sqrtf(cc0), EPS);
        const float icv1 = 1.0f / fmaxf(sqrtf(cc1), EPS);
        sa_acc += cs0 * icv0 + cs1 * icv1;
        if (lane == 0) {
            out_outer[b * C + c0] = cd0 * icv0 * di;
            out_outer[b * C + c0 + 1] = cd1 * icv1 * di;
            ic_lds[c0] = icv0;
            ic_lds[c0 + 1] = icv1;
        }
        // s accumulation in wave-private LDS (cv still in regs)
#pragma unroll
        for (int q = 0; q < 4; ++q) {
            float4 cur = ((float4*)sw)[lane + 64 * q];
            cur.x += cv0[q].x * icv0 + cv1[q].x * icv1;
            cur.y += cv0[q].y * icv0 + cv1[q].y * icv1;
            cur.z += cv0[q].z * icv0 + cv1[q].z * icv1;
            cur.w += cv0[q].w * icv0 + cv1[q].w * icv1;
            ((float4*)sw)[lane + 64 * q] = cur;
        }
    }
    if (lane == 0) sa_lds[wave] = sa_acc;
    __syncthreads();

    // reduce 16 wave partials: thread t owns column t (2-way aliasing = free)
    float colsum = 0.0f;
#pragma unroll
    for (int w = 0; w < NW; ++w) colsum += s_part[w][t];
    s_full[t] = colsum;
    if (t == 0) {
        float S = 0.0f;
#pragma unroll
        for (int w = 0; w < NW; ++w) S += sa_lds[w];
        out_sumavg[b] = S * si * (1.0f / C);
    }
    __syncthreads();

    // ---- Pass C (L3-hot re-read): td = dot(cand_c, s), pairwise ----
#pragma unroll
    for (int p = 0; p < CPW / 2; ++p) {
        const int c0 = wave * CPW + 2 * p;
        const float4* cp0 = cb + (size_t)c0 * (D / 4);
        const float4* cp1 = cp0 + (D / 4);
        float td0 = 0.f, td1 = 0.f;
#pragma unroll
        for (int q = 0; q < 4; ++q) {
            const float4 sv = ((const float4*)s_full)[lane + 64 * q];
            td0 += dot4(cp0[lane + 64 * q], sv);
            td1 += dot4(cp1[lane + 64 * q], sv);
        }
#pragma unroll
        for (int lv = 1; lv <= 32; lv <<= 1) {
            td0 += __shfl_xor(td0, lv, 64);
            td1 += __shfl_xor(td1, lv, 64);
        }
        if (lane == 0) {
            out_inner[b * C + c0] =
                (td0 * ic_lds[c0] - 1.0f) * (1.0f / (C - 1));
            out_inner[b * C + c0 + 1] =
                (td1 * ic_lds[c0 + 1] - 1.0f) * (1.0f / (C - 1));
        }
    }
}

extern "C" void kernel_launch(void* const* d_in, const int* in_sizes, int n_in,
                              void* d_out, int out_size, void* d_ws,
                              size_t ws_size, hipStream_t stream) {
    const float* doc = (const float*)d_in[0];   // [B, D]
    const float* summ = (const float*)d_in[1];  // [B, D]
    const float* cand = (const float*)d_in[2];  // [B, C, D]

    float* out = (float*)d_out;
    float* out_outer = out;                    // [B*C]
    float* out_inner = out + B * C;            // [B*C]
    float* out_sumscore = out + 2 * B * C;     // [B]
    float* out_sumavg = out + 2 * B * C + B;   // [B]

    rerank_all<<<B, 1024, 0, stream>>>(doc, summ, cand, out_outer, out_inner,
                                       out_sumscore, out_sumavg);
}